// Round 2
// baseline (71.115 us; speedup 1.0000x reference)
//
#include <hip/hip_runtime.h>
#include <math.h>

constexpr int Bn = 2048;
constexpr int Nn = 4096;
constexpr int TPB = 1024;          // 16 waves/block, 2 blocks/CU -> 32 waves/CU
constexpr int NWAVES = TPB / 64;

__global__ __launch_bounds__(TPB, 8)
void kabsch_fused(const float* __restrict__ kp,
                  const float* __restrict__ ps,
                  const float* __restrict__ wt,
                  float* __restrict__ out)
{
    const int b   = blockIdx.x;
    const int tid = threadIdx.x;
    const float* kpb = kp + (size_t)b * 3 * Nn;
    const float* psb = ps + (size_t)b * 3 * Nn;
    const float* wb  = wt + (size_t)b * Nn;

    // one float4 chunk per thread: 1024 threads * 4 floats = 4096 = Nn
    const int idx = tid * 4;
    const float4 w4 = *reinterpret_cast<const float4*>(wb + idx);
    const float4 k0 = *reinterpret_cast<const float4*>(kpb + idx);
    const float4 k1 = *reinterpret_cast<const float4*>(kpb + Nn + idx);
    const float4 k2 = *reinterpret_cast<const float4*>(kpb + 2 * Nn + idx);
    const float4 p0 = *reinterpret_cast<const float4*>(psb + idx);
    const float4 p1 = *reinterpret_cast<const float4*>(psb + Nn + idx);
    const float4 p2 = *reinterpret_cast<const float4*>(psb + 2 * Nn + idx);

    // 16 accumulators: [0]=W, [1..3]=Sum w*kp, [4..6]=Sum w*ps, [7..15]=Sum w*kp_i*ps_j
    float acc[16];
#pragma unroll
    for (int i = 0; i < 16; ++i) acc[i] = 0.f;

#define ACCUM(C) do {                                                   \
        const float wj = w4.C;                                          \
        const float a0 = k0.C, a1 = k1.C, a2 = k2.C;                    \
        const float q0 = p0.C, q1 = p1.C, q2 = p2.C;                    \
        const float wa0 = wj * a0, wa1 = wj * a1, wa2 = wj * a2;        \
        acc[0]  += wj;                                                  \
        acc[1]  += wa0;      acc[2]  += wa1;      acc[3]  += wa2;       \
        acc[4]  += wj * q0;  acc[5]  += wj * q1;  acc[6]  += wj * q2;   \
        acc[7]  += wa0 * q0; acc[8]  += wa0 * q1; acc[9]  += wa0 * q2;  \
        acc[10] += wa1 * q0; acc[11] += wa1 * q1; acc[12] += wa1 * q2;  \
        acc[13] += wa2 * q0; acc[14] += wa2 * q1; acc[15] += wa2 * q2;  \
    } while (0)
    ACCUM(x); ACCUM(y); ACCUM(z); ACCUM(w);
#undef ACCUM

    // wave (64-lane) butterfly reduction of the 16 accumulators
#pragma unroll
    for (int i = 0; i < 16; ++i) {
        float v = acc[i];
#pragma unroll
        for (int off = 32; off > 0; off >>= 1) v += __shfl_down(v, off);
        acc[i] = v;
    }

    __shared__ float red[NWAVES][16];
    const int lane = tid & 63;
    const int wid  = tid >> 6;
    if (lane == 0) {
#pragma unroll
        for (int i = 0; i < 16; ++i) red[wid][i] = acc[i];
    }
    __syncthreads();

    // parallel cross-wave sum: threads 0..15 each own one accumulator
    __shared__ double sred[16];
    if (tid < 16) {
        double v = 0.0;
#pragma unroll
        for (int w = 0; w < NWAVES; ++w) v += (double)red[w][tid];
        sred[tid] = v;
    }
    __syncthreads();
    if (tid != 0) return;

    // ---- epilogue: 3x3 Kabsch in fp64, one thread per batch ----
    double s[16];
#pragma unroll
    for (int i = 0; i < 16; ++i) s[i] = sred[i];

    const double W    = s[0];
    const double invW = 1.0 / W;
    double kc[3] = { s[1] * invW, s[2] * invW, s[3] * invW };
    double pc[3] = { s[4] * invW, s[5] * invW, s[6] * invW };
    double H[3][3];
#pragma unroll
    for (int i = 0; i < 3; ++i)
#pragma unroll
        for (int j = 0; j < 3; ++j)
            H[i][j] = s[7 + i * 3 + j] * invW - kc[i] * pc[j];

    // A = H^T H (symmetric)
    double A[3][3];
#pragma unroll
    for (int i = 0; i < 3; ++i)
#pragma unroll
        for (int j = 0; j < 3; ++j)
            A[i][j] = H[0][i] * H[0][j] + H[1][i] * H[1][j] + H[2][i] * H[2][j];

    double V[3][3] = { {1,0,0}, {0,1,0}, {0,0,1} };

    // Jacobi eigendecomposition, constant indices only (stays in registers)
#define JROT(P,Q) do {                                                       \
        const double apq = A[P][Q];                                          \
        if (fabs(apq) > 1e-300) {                                            \
            const double th = (A[Q][Q] - A[P][P]) / (2.0 * apq);             \
            const double tt = copysign(1.0, th) / (fabs(th) + sqrt(1.0 + th * th)); \
            const double c  = 1.0 / sqrt(1.0 + tt * tt);                     \
            const double sn = tt * c;                                        \
            _Pragma("unroll")                                                \
            for (int k = 0; k < 3; ++k) {                                    \
                const double akp = A[k][P], akq = A[k][Q];                   \
                A[k][P] = c * akp - sn * akq;                                \
                A[k][Q] = sn * akp + c * akq;                                \
            }                                                                \
            _Pragma("unroll")                                                \
            for (int k = 0; k < 3; ++k) {                                    \
                const double apk = A[P][k], aqk = A[Q][k];                   \
                A[P][k] = c * apk - sn * aqk;                                \
                A[Q][k] = sn * apk + c * aqk;                                \
            }                                                                \
            _Pragma("unroll")                                                \
            for (int k = 0; k < 3; ++k) {                                    \
                const double vkp = V[k][P], vkq = V[k][Q];                   \
                V[k][P] = c * vkp - sn * vkq;                                \
                V[k][Q] = sn * vkp + c * vkq;                                \
            }                                                                \
        }                                                                    \
    } while (0)

    for (int sweep = 0; sweep < 8; ++sweep) { JROT(0,1); JROT(0,2); JROT(1,2); }
#undef JROT

    double lam[3] = { A[0][0], A[1][1], A[2][2] };
#define CSWAP(I,J) if (lam[I] < lam[J]) {                                    \
        const double tl = lam[I]; lam[I] = lam[J]; lam[J] = tl;              \
        _Pragma("unroll")                                                    \
        for (int k = 0; k < 3; ++k) {                                        \
            const double tv = V[k][I]; V[k][I] = V[k][J]; V[k][J] = tv; }    \
    }
    CSWAP(0, 1); CSWAP(0, 2); CSWAP(1, 2);
#undef CSWAP

    double v0[3] = { V[0][0], V[1][0], V[2][0] };
    double v1[3] = { V[0][1], V[1][1], V[2][1] };
    // right-handed third eigenvector
    double v2[3] = { v0[1] * v1[2] - v0[2] * v1[1],
                     v0[2] * v1[0] - v0[0] * v1[2],
                     v0[0] * v1[1] - v0[1] * v1[0] };

    // u0 = normalize(H v0)
    double u0[3], u1[3];
#pragma unroll
    for (int i = 0; i < 3; ++i)
        u0[i] = H[i][0] * v0[0] + H[i][1] * v0[1] + H[i][2] * v0[2];
    {
        double n0 = sqrt(u0[0]*u0[0] + u0[1]*u0[1] + u0[2]*u0[2]);
        n0 = fmax(n0, 1e-300);
#pragma unroll
        for (int i = 0; i < 3; ++i) u0[i] /= n0;
    }
    // u1 = normalize(H v1 - (u0 . H v1) u0)
    {
        double b1[3];
#pragma unroll
        for (int i = 0; i < 3; ++i)
            b1[i] = H[i][0] * v1[0] + H[i][1] * v1[1] + H[i][2] * v1[2];
        const double dp = u0[0]*b1[0] + u0[1]*b1[1] + u0[2]*b1[2];
#pragma unroll
        for (int i = 0; i < 3; ++i) b1[i] -= dp * u0[i];
        double n1 = sqrt(b1[0]*b1[0] + b1[1]*b1[1] + b1[2]*b1[2]);
        if (n1 > 1e-150) {
#pragma unroll
            for (int i = 0; i < 3; ++i) u1[i] = b1[i] / n1;
        } else {
            // fallback: any unit vector orthogonal to u0
            double e[3] = { 0, 0, 0 };
            if (fabs(u0[0]) <= fabs(u0[1]) && fabs(u0[0]) <= fabs(u0[2])) e[0] = 1;
            else if (fabs(u0[1]) <= fabs(u0[2])) e[1] = 1;
            else e[2] = 1;
            double c1[3] = { u0[1]*e[2] - u0[2]*e[1],
                             u0[2]*e[0] - u0[0]*e[2],
                             u0[0]*e[1] - u0[1]*e[0] };
            double nc = sqrt(c1[0]*c1[0] + c1[1]*c1[1] + c1[2]*c1[2]);
            nc = fmax(nc, 1e-300);
#pragma unroll
            for (int i = 0; i < 3; ++i) u1[i] = c1[i] / nc;
        }
    }

    const double detH =
        H[0][0] * (H[1][1] * H[2][2] - H[1][2] * H[2][1]) -
        H[0][1] * (H[1][0] * H[2][2] - H[1][2] * H[2][0]) +
        H[0][2] * (H[1][0] * H[2][1] - H[1][1] * H[2][0]);
    const double d = (detH < 0.0) ? -1.0 : 1.0;

    // u2 = d * (u0 x u1)
    double u2[3] = { d * (u0[1]*u1[2] - u0[2]*u1[1]),
                     d * (u0[2]*u1[0] - u0[0]*u1[2]),
                     d * (u0[0]*u1[1] - u0[1]*u1[0]) };

    // R = V diag(1,1,d) U^T
    double R[3][3];
#pragma unroll
    for (int i = 0; i < 3; ++i)
#pragma unroll
        for (int j = 0; j < 3; ++j)
            R[i][j] = v0[i] * u0[j] + v1[i] * u1[j] + d * v2[i] * u2[j];

    // t = pc - R kc
    double t[3];
#pragma unroll
    for (int i = 0; i < 3; ++i)
        t[i] = pc[i] - (R[i][0] * kc[0] + R[i][1] * kc[1] + R[i][2] * kc[2]);

    float* outR = out + (size_t)b * 9;
    float* outT = out + (size_t)Bn * 9 + (size_t)b * 3;
#pragma unroll
    for (int i = 0; i < 3; ++i)
#pragma unroll
        for (int j = 0; j < 3; ++j)
            outR[i * 3 + j] = (float)R[i][j];
#pragma unroll
    for (int i = 0; i < 3; ++i) outT[i] = (float)t[i];
}

extern "C" void kernel_launch(void* const* d_in, const int* in_sizes, int n_in,
                              void* d_out, int out_size, void* d_ws, size_t ws_size,
                              hipStream_t stream) {
    const float* kp = (const float*)d_in[0];
    const float* ps = (const float*)d_in[1];
    const float* wt = (const float*)d_in[2];
    float* out = (float*)d_out;
    kabsch_fused<<<Bn, TPB, 0, stream>>>(kp, ps, wt, out);
}

// Round 3
// 60.541 us; speedup vs baseline: 1.1746x; 1.1746x over previous
//
#include <hip/hip_runtime.h>
#include <math.h>

constexpr int Bn = 2048;
constexpr int Nn = 4096;
constexpr int CHUNKS = 2;           // blocks per batch in kernel A
constexpr int TPB_A = 256;          // 4 waves
constexpr int PTS_PER_BLOCK = Nn / CHUNKS;   // 2048 points per block

// ---------------- Kernel A: streaming partial sums ----------------
// grid = Bn*CHUNKS blocks; block (b,c) reduces points [c*2048, c*2048+2048)
// of batch b into 16 partial sums -> ws[(b*CHUNKS+c)*16 + i]
__global__ __launch_bounds__(TPB_A, 8)
void kabsch_stream(const float* __restrict__ kp,
                   const float* __restrict__ ps,
                   const float* __restrict__ wt,
                   float* __restrict__ ws)
{
    const int blk = blockIdx.x;
    const int b   = blk / CHUNKS;
    const int c   = blk % CHUNKS;
    const int tid = threadIdx.x;
    const float* kpb = kp + (size_t)b * 3 * Nn;
    const float* psb = ps + (size_t)b * 3 * Nn;
    const float* wb  = wt + (size_t)b * Nn;

    float acc[16];
#pragma unroll
    for (int i = 0; i < 16; ++i) acc[i] = 0.f;

    // 2 iterations: 256 threads * float4 = 1024 floats per pass
#pragma unroll
    for (int it = 0; it < 2; ++it) {
        const int idx = c * PTS_PER_BLOCK + it * 1024 + tid * 4;
        const float4 w4 = *reinterpret_cast<const float4*>(wb + idx);
        const float4 k0 = *reinterpret_cast<const float4*>(kpb + idx);
        const float4 k1 = *reinterpret_cast<const float4*>(kpb + Nn + idx);
        const float4 k2 = *reinterpret_cast<const float4*>(kpb + 2 * Nn + idx);
        const float4 p0 = *reinterpret_cast<const float4*>(psb + idx);
        const float4 p1 = *reinterpret_cast<const float4*>(psb + Nn + idx);
        const float4 p2 = *reinterpret_cast<const float4*>(psb + 2 * Nn + idx);
#define ACCUM(C) do {                                                   \
        const float wj = w4.C;                                          \
        const float a0 = k0.C, a1 = k1.C, a2 = k2.C;                    \
        const float q0 = p0.C, q1 = p1.C, q2 = p2.C;                    \
        const float wa0 = wj * a0, wa1 = wj * a1, wa2 = wj * a2;        \
        acc[0]  += wj;                                                  \
        acc[1]  += wa0;      acc[2]  += wa1;      acc[3]  += wa2;       \
        acc[4]  += wj * q0;  acc[5]  += wj * q1;  acc[6]  += wj * q2;   \
        acc[7]  += wa0 * q0; acc[8]  += wa0 * q1; acc[9]  += wa0 * q2;  \
        acc[10] += wa1 * q0; acc[11] += wa1 * q1; acc[12] += wa1 * q2;  \
        acc[13] += wa2 * q0; acc[14] += wa2 * q1; acc[15] += wa2 * q2;  \
    } while (0)
        ACCUM(x); ACCUM(y); ACCUM(z); ACCUM(w);
#undef ACCUM
    }

    // wave butterfly reduction
#pragma unroll
    for (int i = 0; i < 16; ++i) {
        float v = acc[i];
#pragma unroll
        for (int off = 32; off > 0; off >>= 1) v += __shfl_down(v, off);
        acc[i] = v;
    }

    __shared__ float red[4][16];
    const int lane = tid & 63;
    const int wid  = tid >> 6;
    if (lane == 0) {
#pragma unroll
        for (int i = 0; i < 16; ++i) red[wid][i] = acc[i];
    }
    __syncthreads();
    if (tid < 16) {
        const float v = red[0][tid] + red[1][tid] + red[2][tid] + red[3][tid];
        ws[(size_t)blk * 16 + tid] = v;
    }
}

// ---------------- Kernel B: parallel 3x3 Kabsch epilogue ----------------
// one THREAD per batch; 2048 threads = 8 blocks x 256
__global__ void kabsch_epilogue(const float* __restrict__ ws,
                                float* __restrict__ out)
{
    const int b = blockIdx.x * blockDim.x + threadIdx.x;
    if (b >= Bn) return;

    const float* p = ws + (size_t)b * CHUNKS * 16;
    double s[16];
#pragma unroll
    for (int i = 0; i < 16; ++i) {
        double v = 0.0;
#pragma unroll
        for (int cidx = 0; cidx < CHUNKS; ++cidx) v += (double)p[cidx * 16 + i];
        s[i] = v;
    }

    const double W    = s[0];
    const double invW = 1.0 / W;
    double kc[3] = { s[1] * invW, s[2] * invW, s[3] * invW };
    double pc[3] = { s[4] * invW, s[5] * invW, s[6] * invW };
    double H[3][3];
#pragma unroll
    for (int i = 0; i < 3; ++i)
#pragma unroll
        for (int j = 0; j < 3; ++j)
            H[i][j] = s[7 + i * 3 + j] * invW - kc[i] * pc[j];

    // A = H^T H (symmetric)
    double A[3][3];
#pragma unroll
    for (int i = 0; i < 3; ++i)
#pragma unroll
        for (int j = 0; j < 3; ++j)
            A[i][j] = H[0][i] * H[0][j] + H[1][i] * H[1][j] + H[2][i] * H[2][j];

    double V[3][3] = { {1,0,0}, {0,1,0}, {0,0,1} };

#define JROT(P,Q) do {                                                       \
        const double apq = A[P][Q];                                          \
        if (fabs(apq) > 1e-300) {                                            \
            const double th = (A[Q][Q] - A[P][P]) / (2.0 * apq);             \
            const double tt = copysign(1.0, th) / (fabs(th) + sqrt(1.0 + th * th)); \
            const double cc = 1.0 / sqrt(1.0 + tt * tt);                     \
            const double sn = tt * cc;                                       \
            _Pragma("unroll")                                                \
            for (int k = 0; k < 3; ++k) {                                    \
                const double akp = A[k][P], akq = A[k][Q];                   \
                A[k][P] = cc * akp - sn * akq;                               \
                A[k][Q] = sn * akp + cc * akq;                               \
            }                                                                \
            _Pragma("unroll")                                                \
            for (int k = 0; k < 3; ++k) {                                    \
                const double apk = A[P][k], aqk = A[Q][k];                   \
                A[P][k] = cc * apk - sn * aqk;                               \
                A[Q][k] = sn * apk + cc * aqk;                               \
            }                                                                \
            _Pragma("unroll")                                                \
            for (int k = 0; k < 3; ++k) {                                    \
                const double vkp = V[k][P], vkq = V[k][Q];                   \
                V[k][P] = cc * vkp - sn * vkq;                               \
                V[k][Q] = sn * vkp + cc * vkq;                               \
            }                                                                \
        }                                                                    \
    } while (0)

    for (int sweep = 0; sweep < 8; ++sweep) { JROT(0,1); JROT(0,2); JROT(1,2); }
#undef JROT

    double lam[3] = { A[0][0], A[1][1], A[2][2] };
#define CSWAP(I,J) if (lam[I] < lam[J]) {                                    \
        const double tl = lam[I]; lam[I] = lam[J]; lam[J] = tl;              \
        _Pragma("unroll")                                                    \
        for (int k = 0; k < 3; ++k) {                                        \
            const double tv = V[k][I]; V[k][I] = V[k][J]; V[k][J] = tv; }    \
    }
    CSWAP(0, 1); CSWAP(0, 2); CSWAP(1, 2);
#undef CSWAP

    double v0[3] = { V[0][0], V[1][0], V[2][0] };
    double v1[3] = { V[0][1], V[1][1], V[2][1] };
    double v2[3] = { v0[1] * v1[2] - v0[2] * v1[1],
                     v0[2] * v1[0] - v0[0] * v1[2],
                     v0[0] * v1[1] - v0[1] * v1[0] };

    double u0[3], u1[3];
#pragma unroll
    for (int i = 0; i < 3; ++i)
        u0[i] = H[i][0] * v0[0] + H[i][1] * v0[1] + H[i][2] * v0[2];
    {
        double n0 = sqrt(u0[0]*u0[0] + u0[1]*u0[1] + u0[2]*u0[2]);
        n0 = fmax(n0, 1e-300);
#pragma unroll
        for (int i = 0; i < 3; ++i) u0[i] /= n0;
    }
    {
        double b1[3];
#pragma unroll
        for (int i = 0; i < 3; ++i)
            b1[i] = H[i][0] * v1[0] + H[i][1] * v1[1] + H[i][2] * v1[2];
        const double dp = u0[0]*b1[0] + u0[1]*b1[1] + u0[2]*b1[2];
#pragma unroll
        for (int i = 0; i < 3; ++i) b1[i] -= dp * u0[i];
        double n1 = sqrt(b1[0]*b1[0] + b1[1]*b1[1] + b1[2]*b1[2]);
        if (n1 > 1e-150) {
#pragma unroll
            for (int i = 0; i < 3; ++i) u1[i] = b1[i] / n1;
        } else {
            double e[3] = { 0, 0, 0 };
            if (fabs(u0[0]) <= fabs(u0[1]) && fabs(u0[0]) <= fabs(u0[2])) e[0] = 1;
            else if (fabs(u0[1]) <= fabs(u0[2])) e[1] = 1;
            else e[2] = 1;
            double c1[3] = { u0[1]*e[2] - u0[2]*e[1],
                             u0[2]*e[0] - u0[0]*e[2],
                             u0[0]*e[1] - u0[1]*e[0] };
            double nc = sqrt(c1[0]*c1[0] + c1[1]*c1[1] + c1[2]*c1[2]);
            nc = fmax(nc, 1e-300);
#pragma unroll
            for (int i = 0; i < 3; ++i) u1[i] = c1[i] / nc;
        }
    }

    const double detH =
        H[0][0] * (H[1][1] * H[2][2] - H[1][2] * H[2][1]) -
        H[0][1] * (H[1][0] * H[2][2] - H[1][2] * H[2][0]) +
        H[0][2] * (H[1][0] * H[2][1] - H[1][1] * H[2][0]);
    const double d = (detH < 0.0) ? -1.0 : 1.0;

    double u2[3] = { d * (u0[1]*u1[2] - u0[2]*u1[1]),
                     d * (u0[2]*u1[0] - u0[0]*u1[2]),
                     d * (u0[0]*u1[1] - u0[1]*u1[0]) };

    double R[3][3];
#pragma unroll
    for (int i = 0; i < 3; ++i)
#pragma unroll
        for (int j = 0; j < 3; ++j)
            R[i][j] = v0[i] * u0[j] + v1[i] * u1[j] + d * v2[i] * u2[j];

    double t[3];
#pragma unroll
    for (int i = 0; i < 3; ++i)
        t[i] = pc[i] - (R[i][0] * kc[0] + R[i][1] * kc[1] + R[i][2] * kc[2]);

    float* outR = out + (size_t)b * 9;
    float* outT = out + (size_t)Bn * 9 + (size_t)b * 3;
#pragma unroll
    for (int i = 0; i < 3; ++i)
#pragma unroll
        for (int j = 0; j < 3; ++j)
            outR[i * 3 + j] = (float)R[i][j];
#pragma unroll
    for (int i = 0; i < 3; ++i) outT[i] = (float)t[i];
}

extern "C" void kernel_launch(void* const* d_in, const int* in_sizes, int n_in,
                              void* d_out, int out_size, void* d_ws, size_t ws_size,
                              hipStream_t stream) {
    const float* kp = (const float*)d_in[0];
    const float* ps = (const float*)d_in[1];
    const float* wt = (const float*)d_in[2];
    float* out = (float*)d_out;
    float* ws  = (float*)d_ws;
    kabsch_stream<<<Bn * CHUNKS, TPB_A, 0, stream>>>(kp, ps, wt, ws);
    kabsch_epilogue<<<(Bn + 255) / 256, 256, 0, stream>>>(ws, out);
}

// Round 4
// 51.356 us; speedup vs baseline: 1.3847x; 1.1788x over previous
//
#include <hip/hip_runtime.h>
#include <math.h>

constexpr int Bn = 2048;
constexpr int Nn = 4096;
constexpr int CHUNKS = 2;           // blocks per batch in kernel A
constexpr int TPB_A = 256;          // 4 waves
constexpr int PTS_PER_BLOCK = Nn / CHUNKS;   // 2048 points per block

// ---------------- Kernel A: streaming partial sums ----------------
// grid = Bn*CHUNKS blocks; block (b,c) reduces points [c*2048, c*2048+2048)
// of batch b into 16 partial sums -> ws[(b*CHUNKS+c)*16 + i]
// All 14 float4 loads are issued up-front into distinct registers so the
// full 14 KB/wave is in flight before the first s_waitcnt (VGPR ~96,
// launch_bounds(256,4) so the compiler doesn't strangle MLP at 32 VGPRs).
__global__ __launch_bounds__(TPB_A, 4)
void kabsch_stream(const float* __restrict__ kp,
                   const float* __restrict__ ps,
                   const float* __restrict__ wt,
                   float* __restrict__ ws)
{
    const int blk = blockIdx.x;
    const int b   = blk / CHUNKS;
    const int c   = blk % CHUNKS;
    const int tid = threadIdx.x;
    const float* kpb = kp + (size_t)b * 3 * Nn;
    const float* psb = ps + (size_t)b * 3 * Nn;
    const float* wb  = wt + (size_t)b * Nn;

    const int idx0 = c * PTS_PER_BLOCK + tid * 4;          // iteration 0
    const int idx1 = idx0 + 1024;                           // iteration 1

    // ---- issue ALL loads before ANY use ----
    const float4 w4a = *reinterpret_cast<const float4*>(wb + idx0);
    const float4 k0a = *reinterpret_cast<const float4*>(kpb + idx0);
    const float4 k1a = *reinterpret_cast<const float4*>(kpb + Nn + idx0);
    const float4 k2a = *reinterpret_cast<const float4*>(kpb + 2 * Nn + idx0);
    const float4 p0a = *reinterpret_cast<const float4*>(psb + idx0);
    const float4 p1a = *reinterpret_cast<const float4*>(psb + Nn + idx0);
    const float4 p2a = *reinterpret_cast<const float4*>(psb + 2 * Nn + idx0);
    const float4 w4b = *reinterpret_cast<const float4*>(wb + idx1);
    const float4 k0b = *reinterpret_cast<const float4*>(kpb + idx1);
    const float4 k1b = *reinterpret_cast<const float4*>(kpb + Nn + idx1);
    const float4 k2b = *reinterpret_cast<const float4*>(kpb + 2 * Nn + idx1);
    const float4 p0b = *reinterpret_cast<const float4*>(psb + idx1);
    const float4 p1b = *reinterpret_cast<const float4*>(psb + Nn + idx1);
    const float4 p2b = *reinterpret_cast<const float4*>(psb + 2 * Nn + idx1);

    float acc[16];
#pragma unroll
    for (int i = 0; i < 16; ++i) acc[i] = 0.f;

#define ACCUM(W4, K0, K1, K2, P0, P1, P2, C) do {                       \
        const float wj = W4.C;                                          \
        const float a0 = K0.C, a1 = K1.C, a2 = K2.C;                    \
        const float q0 = P0.C, q1 = P1.C, q2 = P2.C;                    \
        const float wa0 = wj * a0, wa1 = wj * a1, wa2 = wj * a2;        \
        acc[0]  += wj;                                                  \
        acc[1]  += wa0;      acc[2]  += wa1;      acc[3]  += wa2;       \
        acc[4]  += wj * q0;  acc[5]  += wj * q1;  acc[6]  += wj * q2;   \
        acc[7]  += wa0 * q0; acc[8]  += wa0 * q1; acc[9]  += wa0 * q2;  \
        acc[10] += wa1 * q0; acc[11] += wa1 * q1; acc[12] += wa1 * q2;  \
        acc[13] += wa2 * q0; acc[14] += wa2 * q1; acc[15] += wa2 * q2;  \
    } while (0)
    ACCUM(w4a, k0a, k1a, k2a, p0a, p1a, p2a, x);
    ACCUM(w4a, k0a, k1a, k2a, p0a, p1a, p2a, y);
    ACCUM(w4a, k0a, k1a, k2a, p0a, p1a, p2a, z);
    ACCUM(w4a, k0a, k1a, k2a, p0a, p1a, p2a, w);
    ACCUM(w4b, k0b, k1b, k2b, p0b, p1b, p2b, x);
    ACCUM(w4b, k0b, k1b, k2b, p0b, p1b, p2b, y);
    ACCUM(w4b, k0b, k1b, k2b, p0b, p1b, p2b, z);
    ACCUM(w4b, k0b, k1b, k2b, p0b, p1b, p2b, w);
#undef ACCUM

    // wave butterfly reduction
#pragma unroll
    for (int i = 0; i < 16; ++i) {
        float v = acc[i];
#pragma unroll
        for (int off = 32; off > 0; off >>= 1) v += __shfl_down(v, off);
        acc[i] = v;
    }

    __shared__ float red[4][16];
    const int lane = tid & 63;
    const int wid  = tid >> 6;
    if (lane == 0) {
#pragma unroll
        for (int i = 0; i < 16; ++i) red[wid][i] = acc[i];
    }
    __syncthreads();
    if (tid < 16) {
        const float v = red[0][tid] + red[1][tid] + red[2][tid] + red[3][tid];
        ws[(size_t)blk * 16 + tid] = v;
    }
}

// ---------------- Kernel B: parallel 3x3 Kabsch epilogue ----------------
// one THREAD per batch; 2048 threads = 8 blocks x 256
__global__ void kabsch_epilogue(const float* __restrict__ ws,
                                float* __restrict__ out)
{
    const int b = blockIdx.x * blockDim.x + threadIdx.x;
    if (b >= Bn) return;

    const float* p = ws + (size_t)b * CHUNKS * 16;
    double s[16];
#pragma unroll
    for (int i = 0; i < 16; ++i) {
        double v = 0.0;
#pragma unroll
        for (int cidx = 0; cidx < CHUNKS; ++cidx) v += (double)p[cidx * 16 + i];
        s[i] = v;
    }

    const double W    = s[0];
    const double invW = 1.0 / W;
    double kc[3] = { s[1] * invW, s[2] * invW, s[3] * invW };
    double pc[3] = { s[4] * invW, s[5] * invW, s[6] * invW };
    double H[3][3];
#pragma unroll
    for (int i = 0; i < 3; ++i)
#pragma unroll
        for (int j = 0; j < 3; ++j)
            H[i][j] = s[7 + i * 3 + j] * invW - kc[i] * pc[j];

    // A = H^T H (symmetric)
    double A[3][3];
#pragma unroll
    for (int i = 0; i < 3; ++i)
#pragma unroll
        for (int j = 0; j < 3; ++j)
            A[i][j] = H[0][i] * H[0][j] + H[1][i] * H[1][j] + H[2][i] * H[2][j];

    double V[3][3] = { {1,0,0}, {0,1,0}, {0,0,1} };

#define JROT(P,Q) do {                                                       \
        const double apq = A[P][Q];                                          \
        if (fabs(apq) > 1e-300) {                                            \
            const double th = (A[Q][Q] - A[P][P]) / (2.0 * apq);             \
            const double tt = copysign(1.0, th) / (fabs(th) + sqrt(1.0 + th * th)); \
            const double cc = 1.0 / sqrt(1.0 + tt * tt);                     \
            const double sn = tt * cc;                                       \
            _Pragma("unroll")                                                \
            for (int k = 0; k < 3; ++k) {                                    \
                const double akp = A[k][P], akq = A[k][Q];                   \
                A[k][P] = cc * akp - sn * akq;                               \
                A[k][Q] = sn * akp + cc * akq;                               \
            }                                                                \
            _Pragma("unroll")                                                \
            for (int k = 0; k < 3; ++k) {                                    \
                const double apk = A[P][k], aqk = A[Q][k];                   \
                A[P][k] = cc * apk - sn * aqk;                               \
                A[Q][k] = sn * apk + cc * aqk;                               \
            }                                                                \
            _Pragma("unroll")                                                \
            for (int k = 0; k < 3; ++k) {                                    \
                const double vkp = V[k][P], vkq = V[k][Q];                   \
                V[k][P] = cc * vkp - sn * vkq;                               \
                V[k][Q] = sn * vkp + cc * vkq;                               \
            }                                                                \
        }                                                                    \
    } while (0)

    for (int sweep = 0; sweep < 8; ++sweep) { JROT(0,1); JROT(0,2); JROT(1,2); }
#undef JROT

    double lam[3] = { A[0][0], A[1][1], A[2][2] };
#define CSWAP(I,J) if (lam[I] < lam[J]) {                                    \
        const double tl = lam[I]; lam[I] = lam[J]; lam[J] = tl;              \
        _Pragma("unroll")                                                    \
        for (int k = 0; k < 3; ++k) {                                        \
            const double tv = V[k][I]; V[k][I] = V[k][J]; V[k][J] = tv; }    \
    }
    CSWAP(0, 1); CSWAP(0, 2); CSWAP(1, 2);
#undef CSWAP

    double v0[3] = { V[0][0], V[1][0], V[2][0] };
    double v1[3] = { V[0][1], V[1][1], V[2][1] };
    double v2[3] = { v0[1] * v1[2] - v0[2] * v1[1],
                     v0[2] * v1[0] - v0[0] * v1[2],
                     v0[0] * v1[1] - v0[1] * v1[0] };

    double u0[3], u1[3];
#pragma unroll
    for (int i = 0; i < 3; ++i)
        u0[i] = H[i][0] * v0[0] + H[i][1] * v0[1] + H[i][2] * v0[2];
    {
        double n0 = sqrt(u0[0]*u0[0] + u0[1]*u0[1] + u0[2]*u0[2]);
        n0 = fmax(n0, 1e-300);
#pragma unroll
        for (int i = 0; i < 3; ++i) u0[i] /= n0;
    }
    {
        double b1[3];
#pragma unroll
        for (int i = 0; i < 3; ++i)
            b1[i] = H[i][0] * v1[0] + H[i][1] * v1[1] + H[i][2] * v1[2];
        const double dp = u0[0]*b1[0] + u0[1]*b1[1] + u0[2]*b1[2];
#pragma unroll
        for (int i = 0; i < 3; ++i) b1[i] -= dp * u0[i];
        double n1 = sqrt(b1[0]*b1[0] + b1[1]*b1[1] + b1[2]*b1[2]);
        if (n1 > 1e-150) {
#pragma unroll
            for (int i = 0; i < 3; ++i) u1[i] = b1[i] / n1;
        } else {
            double e[3] = { 0, 0, 0 };
            if (fabs(u0[0]) <= fabs(u0[1]) && fabs(u0[0]) <= fabs(u0[2])) e[0] = 1;
            else if (fabs(u0[1]) <= fabs(u0[2])) e[1] = 1;
            else e[2] = 1;
            double c1[3] = { u0[1]*e[2] - u0[2]*e[1],
                             u0[2]*e[0] - u0[0]*e[2],
                             u0[0]*e[1] - u0[1]*e[0] };
            double nc = sqrt(c1[0]*c1[0] + c1[1]*c1[1] + c1[2]*c1[2]);
            nc = fmax(nc, 1e-300);
#pragma unroll
            for (int i = 0; i < 3; ++i) u1[i] = c1[i] / nc;
        }
    }

    const double detH =
        H[0][0] * (H[1][1] * H[2][2] - H[1][2] * H[2][1]) -
        H[0][1] * (H[1][0] * H[2][2] - H[1][2] * H[2][0]) +
        H[0][2] * (H[1][0] * H[2][1] - H[1][1] * H[2][0]);
    const double d = (detH < 0.0) ? -1.0 : 1.0;

    double u2[3] = { d * (u0[1]*u1[2] - u0[2]*u1[1]),
                     d * (u0[2]*u1[0] - u0[0]*u1[2]),
                     d * (u0[0]*u1[1] - u0[1]*u1[0]) };

    double R[3][3];
#pragma unroll
    for (int i = 0; i < 3; ++i)
#pragma unroll
        for (int j = 0; j < 3; ++j)
            R[i][j] = v0[i] * u0[j] + v1[i] * u1[j] + d * v2[i] * u2[j];

    double t[3];
#pragma unroll
    for (int i = 0; i < 3; ++i)
        t[i] = pc[i] - (R[i][0] * kc[0] + R[i][1] * kc[1] + R[i][2] * kc[2]);

    float* outR = out + (size_t)b * 9;
    float* outT = out + (size_t)Bn * 9 + (size_t)b * 3;
#pragma unroll
    for (int i = 0; i < 3; ++i)
#pragma unroll
        for (int j = 0; j < 3; ++j)
            outR[i * 3 + j] = (float)R[i][j];
#pragma unroll
    for (int i = 0; i < 3; ++i) outT[i] = (float)t[i];
}

extern "C" void kernel_launch(void* const* d_in, const int* in_sizes, int n_in,
                              void* d_out, int out_size, void* d_ws, size_t ws_size,
                              hipStream_t stream) {
    const float* kp = (const float*)d_in[0];
    const float* ps = (const float*)d_in[1];
    const float* wt = (const float*)d_in[2];
    float* out = (float*)d_out;
    float* ws  = (float*)d_ws;
    kabsch_stream<<<Bn * CHUNKS, TPB_A, 0, stream>>>(kp, ps, wt, ws);
    kabsch_epilogue<<<(Bn + 255) / 256, 256, 0, stream>>>(ws, out);
}